// Round 10
// baseline (732.557 us; speedup 1.0000x reference)
//
#include <hip/hip_runtime.h>
#include <math.h>

namespace {

typedef unsigned short bf16_t;
typedef __bf16  bf16x8_t __attribute__((ext_vector_type(8)));
typedef float   f32x4_t  __attribute__((ext_vector_type(4)));
typedef unsigned int u32x4 __attribute__((ext_vector_type(4)));

constexpr int G     = 4096;      // BS*E
constexpr int GA    = 32768;     // G*A
constexpr int WDIM  = 300;
constexpr int KPAD  = 320;
constexpr int HDIM  = 1024;
constexpr int NNODE = 9;
constexpr int MROWS = G * NNODE; // 36864
constexpr int TE_   = 8;
constexpr int TA_   = 4;
constexpr int V_    = 30522;
constexpr int VP    = 30592;     // 239*128
constexpr int PROJW = 1024;

__device__ __forceinline__ float bf2f(bf16_t b) {
    union { unsigned int u; float f; } v; v.u = ((unsigned int)b) << 16; return v.f;
}
__device__ __forceinline__ bf16_t f2bf(float f) {
    union { float f; unsigned int u; } v; v.f = f;
    unsigned int r = v.u + 0x7FFFu + ((v.u >> 16) & 1u);   // RNE
    return (bf16_t)(r >> 16);
}

// R18 fast gates: v_exp + v_rcp (err ~1e-7, << bf16 quantum 4e-3).
__device__ __forceinline__ float fast_sigmoid(float x) {
    return __builtin_amdgcn_rcpf(1.f + __expf(-x));
}
__device__ __forceinline__ float fast_tanh(float x) {
    return 1.f - 2.f * __builtin_amdgcn_rcpf(1.f + __expf(2.f * x));
}

// =====================================================================
// Generic 128x128-tile bf16 MFMA GEMM: C = A[M,K] @ B[N,K]^T
// MODE 0: C bf16 (vocab projection)   MODE 2: C fp32 with elu (final out)
// R16: LDS row stride 40. R18: register prefetch of next k-tile.
// =====================================================================
template<int MODE>
__global__ __launch_bounds__(256)
void mfma_gemm(const bf16_t* __restrict__ A, const bf16_t* __restrict__ B,
               void* __restrict__ Cv, int lda, int ldb, int ldc, int K)
{
    constexpr int AST = 40;                  // padded LDS row stride (bf16)
    __shared__ __align__(16) bf16_t As[128 * AST];   // 10 KB
    __shared__ __align__(16) bf16_t Bs[128 * AST];   // 10 KB

    const int tid  = threadIdx.x;
    const int w    = tid >> 6;
    const int lane = tid & 63;
    const int wr = w >> 1, wc = w & 1;
    const int lr = lane & 15;
    const int lk = lane >> 4;
    const int m0 = blockIdx.x * 128, n0 = blockIdx.y * 128;

    const int r0 = tid >> 2;
    const int cc = (tid & 3) * 8;
    const bf16_t* Arow0 = A + (size_t)(m0 + r0) * lda + cc;
    const bf16_t* Arow1 = Arow0 + (size_t)64 * lda;
    const bf16_t* Brow0 = B + (size_t)(n0 + r0) * ldb + cc;
    const bf16_t* Brow1 = Brow0 + (size_t)64 * ldb;

    f32x4_t acc[4][4];
#pragma unroll
    for (int i = 0; i < 4; ++i)
#pragma unroll
        for (int j = 0; j < 4; ++j) acc[i][j] = {0.f, 0.f, 0.f, 0.f};

    uint4 a0 = *(const uint4*)(Arow0);
    uint4 a1 = *(const uint4*)(Arow1);
    uint4 b0 = *(const uint4*)(Brow0);
    uint4 b1 = *(const uint4*)(Brow1);

    for (int k0 = 0; k0 < K; k0 += 32) {
        __syncthreads();
        *(uint4*)&As[r0 * AST + cc]        = a0;
        *(uint4*)&As[(r0 + 64) * AST + cc] = a1;
        *(uint4*)&Bs[r0 * AST + cc]        = b0;
        *(uint4*)&Bs[(r0 + 64) * AST + cc] = b1;
        if (k0 + 32 < K) {                   // prefetch next tile (hidden by MFMA)
            a0 = *(const uint4*)(Arow0 + k0 + 32);
            a1 = *(const uint4*)(Arow1 + k0 + 32);
            b0 = *(const uint4*)(Brow0 + k0 + 32);
            b1 = *(const uint4*)(Brow1 + k0 + 32);
        }
        __syncthreads();

        bf16x8_t af[4], bfr[4];
#pragma unroll
        for (int i = 0; i < 4; ++i) {
            af[i]  = *(const bf16x8_t*)&As[(wr * 64 + i * 16 + lr) * AST + lk * 8];
            bfr[i] = *(const bf16x8_t*)&Bs[(wc * 64 + i * 16 + lr) * AST + lk * 8];
        }
#pragma unroll
        for (int mi = 0; mi < 4; ++mi)
#pragma unroll
            for (int ni = 0; ni < 4; ++ni)
                acc[mi][ni] = __builtin_amdgcn_mfma_f32_16x16x32_bf16(
                    af[mi], bfr[ni], acc[mi][ni], 0, 0, 0);
    }

#pragma unroll
    for (int mi = 0; mi < 4; ++mi) {
#pragma unroll
        for (int ni = 0; ni < 4; ++ni) {
            const int n = n0 + wc * 64 + ni * 16 + lr;
#pragma unroll
            for (int r = 0; r < 4; ++r) {
                const int m = m0 + wr * 64 + mi * 16 + lk * 4 + r;
                const float v = acc[mi][ni][r];
                if (MODE == 0)
                    ((bf16_t*)Cv)[(size_t)m * ldc + n] = f2bf(v);
                else
                    ((float*)Cv)[(size_t)m * ldc + n] = v > 0.f ? v : expm1f(v);
            }
        }
    }
}

// =====================================================================
// GRU step (used for BOTH ent and attr). One launch per step; fused
// GEMM + gate epilogue. gates[M x 960] = h @ Whh3i^T, tile 128x120
// (interleaved n=3j+g), grid (M/128, 8), 512 thr. Scatter col<120 (R12).
// R19 post-mortem of R18: VGPR_Count=52 proved the T14 prefetch never
// survived regalloc — xw/hw loads were sunk back to the epilogue, so
// the random proj-gather latency stayed exposed. And the 5.65M bank
// conflicts live in the gsm SCATTER (GSTRF=123: lk bank offsets
// {0,12,24,4} -> multi-way), not As/Bs (R17 null).
// R19: (a) GSTRF 123->124: 4*124 mod 32 = 16 -> lk offsets {0,16,0,16}
// -> every scatter write exactly 2-way (free). 63488B keeps 2 blk/CU.
// (b) __launch_bounds__(512,4) (~128 VGPR budget at unchanged
// residency) + asm liveness pins on xw/hw to force issue BEFORE the
// GEMM (T14 for real this time).
// =====================================================================
__global__ __launch_bounds__(512, 4)
void gru_step_fused(const bf16_t* __restrict__ hin,     // [M][KPAD]
                    bf16_t* __restrict__ hout,          // [M][KPAD]
                    const bf16_t* __restrict__ Whh3i,   // [1024][320] n=3j+g
                    const bf16_t* __restrict__ proj,    // [VP][1024]  n=3j+g
                    const int* __restrict__ tokens,
                    const int* __restrict__ lengths,
                    const float* __restrict__ bih, const float* __restrict__ bhh,
                    int T, int t)
{
    constexpr int GSTRF = 124;               // f32 stride: 4*124%32==16 -> 2-way scatter
    __shared__ __align__(16) bf16_t As[128 * 32];   // 8 KB
    __shared__ __align__(16) bf16_t Bs[128 * 32];   // 8 KB
    __shared__ float gsm[128 * GSTRF];              // 62 KB (79872 B total: 2 blk/CU)

    const int tid = threadIdx.x;
    const int w = tid >> 6, lane = tid & 63;
    const int lr = lane & 15, lk = lane >> 4;
    const int wr = w >> 2, wc = w & 3;       // 2 (M) x 4 (N) waves
    const int m0 = blockIdx.x * 128;
    const int nb = blockIdx.y;               // 0..7
    const int n0 = nb * 120;

    // ---- T14 prefetch: issue epilogue loads BEFORE the GEMM, pinned ----
    const int ml = tid >> 2, q = tid & 3;
    const int m  = m0 + ml;
    const int jb = nb * 40 + q * 10;
    const bool estore = !(nb == 7 && q >= 2);   // j >= 300 never stored
    int len = lengths[m]; if (len < 1) len = 1;
    const bool act = (t < len);
    const int tok = tokens[(size_t)m * T + t];

    const unsigned int* xpp =
        (const unsigned int*)(proj + (size_t)tok * PROJW + n0 + q * 30);
    unsigned int xw[15];
#pragma unroll
    for (int i = 0; i < 15; ++i) xw[i] = xpp[i];

    const unsigned int* hop = (const unsigned int*)(hin + (size_t)m * KPAD + jb);
    unsigned int hw[5];
#pragma unroll
    for (int i = 0; i < 5; ++i) hw[i] = hop[i];

    // pin: force the gathers to materialize here (before the GEMM) so the
    // ~900cyc random-row latency hides under the k-loop. Without this the
    // allocator sinks them to the epilogue (R18: VGPR=52 proved it).
#pragma unroll
    for (int i = 0; i < 15; ++i) asm volatile("" : "+v"(xw[i]));
#pragma unroll
    for (int i = 0; i < 5; ++i)  asm volatile("" : "+v"(hw[i]));

    // ---- GEMM with register-prefetched staging ----
    const int sr = tid >> 2, sq = tid & 3;   // staging row / 16B-slot
    const bf16_t* Ap = hin   + (size_t)(m0 + sr) * KPAD + sq * 8;
    const bf16_t* Bp = Whh3i + (size_t)(n0 + sr) * KPAD + sq * 8;
    const int ssl = (sq ^ (sr & 3)) * 8;     // swizzled staging slot

    f32x4_t acc[4][2];
#pragma unroll
    for (int mi = 0; mi < 4; ++mi)
#pragma unroll
        for (int ni = 0; ni < 2; ++ni) acc[mi][ni] = {0.f, 0.f, 0.f, 0.f};

    uint4 av = *(const uint4*)(Ap);
    uint4 bv = *(const uint4*)(Bp);

    for (int k0 = 0; k0 < KPAD; k0 += 32) {
        __syncthreads();
        *(uint4*)&As[sr * 32 + ssl] = av;
        *(uint4*)&Bs[sr * 32 + ssl] = bv;
        if (k0 + 32 < KPAD) {                // prefetch next k-tile
            av = *(const uint4*)(Ap + k0 + 32);
            bv = *(const uint4*)(Bp + k0 + 32);
        }
        __syncthreads();

        // read slot swizzle: row&3 == lr&3 (row bases are multiples of 4)
        const int asl = (lk ^ (lr & 3)) * 8;
        bf16x8_t af[4], bfr[2];
#pragma unroll
        for (int mi = 0; mi < 4; ++mi)
            af[mi] = *(const bf16x8_t*)&As[(wr * 64 + mi * 16 + lr) * 32 + asl];
#pragma unroll
        for (int ni = 0; ni < 2; ++ni)
            bfr[ni] = *(const bf16x8_t*)&Bs[(wc * 32 + ni * 16 + lr) * 32 + asl];
#pragma unroll
        for (int mi = 0; mi < 4; ++mi)
#pragma unroll
            for (int ni = 0; ni < 2; ++ni)
                acc[mi][ni] = __builtin_amdgcn_mfma_f32_16x16x32_bf16(
                    af[mi], bfr[ni], acc[mi][ni], 0, 0, 0);
    }

    // scatter wave tiles to gates LDS (row = M, col = N); cols >= 120 are
    // the B-stage overlap belonging to the next nb block — DO NOT scatter
#pragma unroll
    for (int ni = 0; ni < 2; ++ni) {
        const int col = wc * 32 + ni * 16 + lr;
        if (col < 120) {
#pragma unroll
            for (int mi = 0; mi < 4; ++mi)
#pragma unroll
                for (int r = 0; r < 4; ++r)
                    gsm[(wr * 64 + mi * 16 + lk * 4 + r) * GSTRF + col]
                        = acc[mi][ni][r];
        }
    }
    __syncthreads();

    // ---- fused GRU epilogue (fast gates, prefetched operands) ----
    unsigned int ow[5];
#pragma unroll
    for (int u = 0; u < 10; ++u) {
        const int j = jb + u;
        const bf16_t hob = (bf16_t)((u & 1) ? (hw[u >> 1] >> 16) : (hw[u >> 1] & 0xffff));
        const float hold = bf2f(hob);
        float hv = hold;
        if (act) {
            const int e0 = 3 * u;
            const float xr = bf2f((bf16_t)((e0 & 1)       ? (xw[e0 >> 1] >> 16)       : (xw[e0 >> 1] & 0xffff)));
            const float xz = bf2f((bf16_t)(((e0 + 1) & 1) ? (xw[(e0 + 1) >> 1] >> 16) : (xw[(e0 + 1) >> 1] & 0xffff)));
            const float xn = bf2f((bf16_t)(((e0 + 2) & 1) ? (xw[(e0 + 2) >> 1] >> 16) : (xw[(e0 + 2) >> 1] & 0xffff)));
            const int nl = q * 30 + 3 * u;
            const float g0 = gsm[ml * GSTRF + nl];
            const float g1 = gsm[ml * GSTRF + nl + 1];
            const float g2 = gsm[ml * GSTRF + nl + 2];
            const float rr = fast_sigmoid(g0 + xr + bih[j] + bhh[j]);
            const float zz = fast_sigmoid(g1 + xz + bih[WDIM + j] + bhh[WDIM + j]);
            const float nn = fast_tanh(xn + bih[2 * WDIM + j] + rr * (g2 + bhh[2 * WDIM + j]));
            hv = (1.f - zz) * nn + zz * hold;
        }
        const bf16_t hb_ = f2bf(hv);
        if ((u & 1) == 0) ow[u >> 1] = hb_;
        else              ow[u >> 1] |= ((unsigned int)hb_) << 16;
    }
    if (estore) {
        unsigned int* outp = (unsigned int*)(hout + (size_t)m * KPAD + jb);
#pragma unroll
        for (int i = 0; i < 5; ++i) outp[i] = ow[i];
    }
}

// =====================================================================
// R16: nodes = relu(h @ Wfc^T + bfc) as a PROPER 128x128 GEMM with a
// gathered A (128-entry LDS pointer table). Stride-40 LDS.
// R18: register prefetch of next k-tile.
// =====================================================================
__global__ __launch_bounds__(256)
void fc_nodes_gemm(const bf16_t* __restrict__ hEnt, const bf16_t* __restrict__ hAtt,
                   const bf16_t* __restrict__ WfcB, const float* __restrict__ bfc,
                   bf16_t* __restrict__ nodes)
{
    constexpr int AST = 40;
    __shared__ __align__(16) bf16_t As[128 * AST];   // 10 KB
    __shared__ __align__(16) bf16_t Bs[128 * AST];   // 10 KB
    __shared__ const bf16_t* rowp[128];

    const int tid  = threadIdx.x;
    const int w    = tid >> 6;
    const int lane = tid & 63;
    const int wr = w >> 1, wc = w & 1;
    const int lr = lane & 15;
    const int lk = lane >> 4;
    const int m0 = blockIdx.x * 128, n0 = blockIdx.y * 128;

    if (tid < 128) {
        const int m = m0 + tid;
        const int g = m / NNODE, i = m - g * NNODE;
        rowp[tid] = (i == 0) ? (hEnt + (size_t)g * KPAD)
                             : (hAtt + (size_t)(g * 8 + (i - 1)) * KPAD);
    }
    __syncthreads();

    const int r0 = tid >> 2;
    const int cc = (tid & 3) * 8;
    const bf16_t* Arow0 = rowp[r0] + cc;
    const bf16_t* Arow1 = rowp[r0 + 64] + cc;
    const bf16_t* Brow0 = WfcB + (size_t)(n0 + r0) * KPAD + cc;
    const bf16_t* Brow1 = Brow0 + (size_t)64 * KPAD;

    f32x4_t acc[4][4];
#pragma unroll
    for (int i = 0; i < 4; ++i)
#pragma unroll
        for (int j = 0; j < 4; ++j) acc[i][j] = {0.f, 0.f, 0.f, 0.f};

    uint4 a0 = *(const uint4*)(Arow0);
    uint4 a1 = *(const uint4*)(Arow1);
    uint4 b0 = *(const uint4*)(Brow0);
    uint4 b1 = *(const uint4*)(Brow1);

    for (int k0 = 0; k0 < KPAD; k0 += 32) {
        __syncthreads();
        *(uint4*)&As[r0 * AST + cc]        = a0;
        *(uint4*)&As[(r0 + 64) * AST + cc] = a1;
        *(uint4*)&Bs[r0 * AST + cc]        = b0;
        *(uint4*)&Bs[(r0 + 64) * AST + cc] = b1;
        if (k0 + 32 < KPAD) {
            a0 = *(const uint4*)(Arow0 + k0 + 32);
            a1 = *(const uint4*)(Arow1 + k0 + 32);
            b0 = *(const uint4*)(Brow0 + k0 + 32);
            b1 = *(const uint4*)(Brow1 + k0 + 32);
        }
        __syncthreads();

        bf16x8_t af[4], bfr[4];
#pragma unroll
        for (int i = 0; i < 4; ++i) {
            af[i]  = *(const bf16x8_t*)&As[(wr * 64 + i * 16 + lr) * AST + lk * 8];
            bfr[i] = *(const bf16x8_t*)&Bs[(wc * 64 + i * 16 + lr) * AST + lk * 8];
        }
#pragma unroll
        for (int mi = 0; mi < 4; ++mi)
#pragma unroll
            for (int ni = 0; ni < 4; ++ni)
                acc[mi][ni] = __builtin_amdgcn_mfma_f32_16x16x32_bf16(
                    af[mi], bfr[ni], acc[mi][ni], 0, 0, 0);
    }

#pragma unroll
    for (int mi = 0; mi < 4; ++mi) {
#pragma unroll
        for (int ni = 0; ni < 4; ++ni) {
            const int n = n0 + wc * 64 + ni * 16 + lr;
            const float bb = bfc[n];
#pragma unroll
            for (int r = 0; r < 4; ++r) {
                const int m = m0 + wr * 64 + mi * 16 + lk * 4 + r;
                float v = acc[mi][ni][r] + bb;
                v = v > 0.f ? v : 0.f;
                nodes[(size_t)m * HDIM + n] = f2bf(v);
            }
        }
    }
}

// es[m] = nodes[m] . asW ; ed[m] = nodes[m] . adW. One wave per row.
__global__ __launch_bounds__(256)
void esed_kernel(const bf16_t* __restrict__ nodes,
                 const float* __restrict__ asW, const float* __restrict__ adW,
                 float* __restrict__ es, float* __restrict__ ed)
{
    const int m    = (blockIdx.x * 256 + threadIdx.x) >> 6;   // row
    const int lane = threadIdx.x & 63;
    const bf16_t* row = nodes + (size_t)m * HDIM;

    const uint4 v0 = *(const uint4*)(row + lane * 8);
    const uint4 v1 = *(const uint4*)(row + 512 + lane * 8);

    float s = 0.f, d = 0.f;
    const unsigned int* w0 = (const unsigned int*)&v0;
    const unsigned int* w1 = (const unsigned int*)&v1;
#pragma unroll
    for (int e = 0; e < 4; ++e) {
        const int c0 = lane * 8 + 2 * e;
        const float x0 = bf2f((bf16_t)(w0[e] & 0xffff));
        const float x1 = bf2f((bf16_t)(w0[e] >> 16));
        s = fmaf(x0, asW[c0], s);     s = fmaf(x1, asW[c0 + 1], s);
        d = fmaf(x0, adW[c0], d);     d = fmaf(x1, adW[c0 + 1], d);
        const int c1 = 512 + lane * 8 + 2 * e;
        const float y0 = bf2f((bf16_t)(w1[e] & 0xffff));
        const float y1 = bf2f((bf16_t)(w1[e] >> 16));
        s = fmaf(y0, asW[c1], s);     s = fmaf(y1, asW[c1 + 1], s);
        d = fmaf(y0, adW[c1], d);     d = fmaf(y1, adW[c1 + 1], d);
    }
#pragma unroll
    for (int mask = 1; mask < 64; mask <<= 1) {
        s += __shfl_xor(s, mask, 64);
        d += __shfl_xor(d, mask, 64);
    }
    if (lane == 0) { es[m] = s; ed[m] = d; }
}

// =====================================================================
// Prep kernels
// =====================================================================
__global__ __launch_bounds__(256)
void convert_emb_kernel(const float* __restrict__ emb, bf16_t* __restrict__ embB)
{
    const int idx = blockIdx.x * 256 + threadIdx.x;    // over V_*40
    if (idx >= V_ * 40) return;
    const int row = idx / 40, c8 = (idx - row * 40) * 8;
    bf16_t o[8];
#pragma unroll
    for (int e = 0; e < 8; ++e) {
        const int c = c8 + e;
        o[e] = (c < WDIM) ? f2bf(emb[(size_t)row * WDIM + c]) : (bf16_t)0;
    }
    *(ushort4*)(embB + (size_t)row * KPAD + c8)     = *(ushort4*)&o[0];
    *(ushort4*)(embB + (size_t)row * KPAD + c8 + 4) = *(ushort4*)&o[4];
}

// W [3*300][300] fp32 -> dst[1024][320] bf16, INTERLEAVED rows n = 3*j + g
__global__ __launch_bounds__(256)
void build_w3i_kernel(const float* __restrict__ W, bf16_t* __restrict__ dst)
{
    const int idx = blockIdx.x * 256 + threadIdx.x;    // over 1024*320
    if (idx >= HDIM * KPAD) return;
    const int n = idx / KPAD, k = idx - n * KPAD;
    float v = 0.f;
    if (n < 960) {
        const int j = n / 3, g = n - j * 3;
        if (j < WDIM && k < WDIM)
            v = W[(size_t)(g * WDIM + j) * WDIM + k];
    }
    dst[idx] = f2bf(v);
}

__global__ __launch_bounds__(256)
void build_wfc_kernel(const float* __restrict__ Wfc, bf16_t* __restrict__ Wb)
{
    const int idx = blockIdx.x * 256 + threadIdx.x;    // over 1024*320
    if (idx >= HDIM * KPAD) return;
    const int n = idx / KPAD, k = idx - n * KPAD;
    Wb[idx] = f2bf(k < WDIM ? Wfc[(size_t)n * WDIM + k] : 0.f);
}

__global__ __launch_bounds__(256)
void build_wg_kernel(const float* __restrict__ Wg, bf16_t* __restrict__ Wb)
{
    const int idx = blockIdx.x * 256 + threadIdx.x;    // over 1024*1024
    Wb[idx] = f2bf(Wg[idx]);
}

// asW = a_src @ Wg, adW = a_dst @ Wg
__global__ __launch_bounds__(256)
void asw_kernel(const float* __restrict__ Wg,
                const float* __restrict__ a_src, const float* __restrict__ a_dst,
                float* __restrict__ asW, float* __restrict__ adW)
{
    const int k = blockIdx.x * 256 + threadIdx.x;
    float s = 0.f, d = 0.f;
    for (int n = 0; n < HDIM; ++n) {
        const float w = Wg[(size_t)n * HDIM + k];
        s = fmaf(a_src[n], w, s);
        d = fmaf(a_dst[n], w, d);
    }
    asW[k] = s; adW[k] = d;
}

// Row-0 star attention -> mixed[g] = sum_j alpha_j * nodes[g*9+j] (bf16)
__global__ __launch_bounds__(256)
void attn_mix_kernel(const bf16_t* __restrict__ nodes,
                     const float* __restrict__ es, const float* __restrict__ ed,
                     bf16_t* __restrict__ mixed)
{
    const int g = blockIdx.x;
    const float e0 = es[(size_t)g * NNODE];
    const float* edg = ed + (size_t)g * NNODE;

    float w[NNODE], mx = -1e30f;
#pragma unroll
    for (int j = 0; j < NNODE; ++j) {
        float v = e0 + edg[j];
        v = v >= 0.f ? v : 0.2f * v;
        w[j] = v; mx = fmaxf(mx, v);
    }
    float denom = 0.f;
#pragma unroll
    for (int j = 0; j < NNODE; ++j) { w[j] = expf(w[j] - mx); denom += w[j]; }
    const float inv = 1.f / denom;

    const int c = threadIdx.x * 4;
    float4 acc = {0.f, 0.f, 0.f, 0.f};
#pragma unroll
    for (int j = 0; j < NNODE; ++j) {
        const float a = w[j] * inv;
        const ushort4 h4 = *(const ushort4*)(nodes + (size_t)(g * NNODE + j) * HDIM + c);
        acc.x = fmaf(a, bf2f(h4.x), acc.x);
        acc.y = fmaf(a, bf2f(h4.y), acc.y);
        acc.z = fmaf(a, bf2f(h4.z), acc.z);
        acc.w = fmaf(a, bf2f(h4.w), acc.w);
    }
    ushort4 o;
    o.x = f2bf(acc.x); o.y = f2bf(acc.y); o.z = f2bf(acc.z); o.w = f2bf(acc.w);
    *(ushort4*)(mixed + (size_t)g * HDIM + c) = o;
}

// -------- workspace layout (~134 MiB; 157 MiB known-safe) --------
constexpr size_t SZ_EMBB  = (size_t)VP * KPAD * sizeof(bf16_t);      // 19.58 MB
constexpr size_t SZ_PROJ  = (size_t)VP * PROJW * sizeof(bf16_t);     // 62.65 MB
constexpr size_t SZ_HATT  = (size_t)GA * KPAD * sizeof(bf16_t);      // 20.97 MB x2
constexpr size_t SZ_HENT  = (size_t)G * KPAD * sizeof(bf16_t);       //  2.62 MB x2
constexpr size_t SZ_WIH3  = (size_t)HDIM * KPAD * sizeof(bf16_t);
constexpr size_t SZ_WHH3E = (size_t)HDIM * KPAD * sizeof(bf16_t);    //  0.66 MB x2 (1024 rows)
constexpr size_t SZ_WFC   = (size_t)HDIM * KPAD * sizeof(bf16_t);
constexpr size_t SZ_WG    = (size_t)HDIM * HDIM * sizeof(bf16_t);
constexpr size_t SZ_AW    = (size_t)HDIM * sizeof(float);
constexpr size_t SZ_VEC   = (size_t)MROWS * sizeof(float);
constexpr size_t SZ_NODE  = (size_t)MROWS * HDIM * sizeof(bf16_t);   // 75.5 MB
constexpr size_t SZ_MIX   = (size_t)G * HDIM * sizeof(bf16_t);
constexpr size_t WS_NEED  = SZ_EMBB + SZ_PROJ + 2 * SZ_HATT + 2 * SZ_HENT +
                            SZ_WIH3 + 2 * SZ_WHH3E + SZ_WFC + SZ_WG +
                            2 * SZ_AW + 2 * SZ_VEC;
static_assert(SZ_NODE <= SZ_EMBB + SZ_PROJ, "nodes overlays embB+proj");
static_assert(SZ_MIX  <= 2 * SZ_HATT,       "mixed overlays hAtt pair");

} // namespace

extern "C" void kernel_launch(void* const* d_in, const int* in_sizes, int n_in,
                              void* d_out, int out_size, void* d_ws, size_t ws_size,
                              hipStream_t stream)
{
    (void)in_sizes; (void)n_in; (void)out_size;
    if (ws_size < WS_NEED) return;   // clean absmax failure instead of fault

    const int*   ent_tok  = (const int*)  d_in[0];
    const int*   ent_len  = (const int*)  d_in[1];
    const int*   at_tok   = (const int*)  d_in[3];
    const int*   at_len   = (const int*)  d_in[4];
    const float* emb      = (const float*)d_in[6];
    const float* Wih_ent  = (const float*)d_in[7];
    const float* Whh_ent  = (const float*)d_in[8];
    const float* bih_ent  = (const float*)d_in[9];
    const float* bhh_ent  = (const float*)d_in[10];
    const float* Wih_attr = (const float*)d_in[11];
    const float* Whh_attr = (const float*)d_in[12];
    const float* bih_attr = (const float*)d_in[13];
    const float* bhh_attr = (const float*)d_in[14];
    const float* Wfc      = (const float*)d_in[15];
    const float* bfc      = (const float*)d_in[16];
    const float* Wg       = (const float*)d_in[17];
    const float* a_src    = (const float*)d_in[18];
    const float* a_dst    = (const float*)d_in[19];
    float* out = (float*)d_out;

    char* p = (char*)d_ws;
    bf16_t* embB  = (bf16_t*)p; p += SZ_EMBB;
    bf16_t* proj  = (bf16_t*)p; p += SZ_PROJ;
    bf16_t* hAtt[2];
    hAtt[0] = (bf16_t*)p; p += SZ_HATT;
    hAtt[1] = (bf16_t*)p; p += SZ_HATT;
    bf16_t* hEnt   = (bf16_t*)p; p += SZ_HENT;
    bf16_t* hEnt2  = (bf16_t*)p; p += SZ_HENT;
    bf16_t* Wih3   = (bf16_t*)p; p += SZ_WIH3;
    bf16_t* Whh3_a = (bf16_t*)p; p += SZ_WHH3E;
    bf16_t* Whh3_e = (bf16_t*)p; p += SZ_WHH3E;
    bf16_t* WfcB   = (bf16_t*)p; p += SZ_WFC;
    bf16_t* WgB    = (bf16_t*)p; p += SZ_WG;
    float*  asW    = (float*)p;  p += SZ_AW;
    float*  adW    = (float*)p;  p += SZ_AW;
    float*  es     = (float*)p;  p += SZ_VEC;
    float*  ed     = (float*)p;  p += SZ_VEC;
    bf16_t* nodes  = embB;       // overlay: embB+proj dead after GRU loops
    bf16_t* mixed  = hAtt[0];    // overlay: hAtt dead after fc_nodes_gemm

    // zero h ping-pong buffers (h0 = 0; pad cols must stay 0)
    hipMemsetAsync(hAtt[0], 0, SZ_HATT, stream);
    hipMemsetAsync(hAtt[1], 0, SZ_HATT, stream);
    hipMemsetAsync(hEnt,  0, SZ_HENT, stream);
    hipMemsetAsync(hEnt2, 0, SZ_HENT, stream);

    // prep (both GRUs use the INTERLEAVED n=3j+g layout)
    convert_emb_kernel<<<dim3((V_ * 40 + 255) / 256), 256, 0, stream>>>(emb, embB);
    build_w3i_kernel<<<dim3(HDIM * KPAD / 256), 256, 0, stream>>>(Wih_attr, Wih3);
    build_w3i_kernel<<<dim3(HDIM * KPAD / 256), 256, 0, stream>>>(Whh_attr, Whh3_a);
    build_w3i_kernel<<<dim3(HDIM * KPAD / 256), 256, 0, stream>>>(Whh_ent, Whh3_e);
    build_wfc_kernel<<<dim3(HDIM * KPAD / 256), 256, 0, stream>>>(Wfc, WfcB);
    build_wg_kernel<<<dim3(HDIM * HDIM / 256), 256, 0, stream>>>(Wg, WgB);
    asw_kernel<<<dim3(HDIM / 256), 256, 0, stream>>>(Wg, a_src, a_dst, asW, adW);

    // attr vocab projection (interleaved): proj[v] = embB[v] @ Wih3i_attr^T
    mfma_gemm<0><<<dim3(VP / 128, PROJW / 128), 256, 0, stream>>>(
        embB, Wih3, proj, KPAD, KPAD, PROJW, KPAD);

    // attr GRU: T=4 fused GEMM+epilogue steps, grid 256x8 = 2048 blocks
    for (int t = 0; t < TA_; ++t)
        gru_step_fused<<<dim3(GA / 128, 8), 512, 0, stream>>>(
            hAtt[t & 1], hAtt[(t + 1) & 1], Whh3_a, proj, at_tok, at_len,
            bih_attr, bhh_attr, TA_, t);

    // ent vocab projection (interleaved); overwrite proj
    build_w3i_kernel<<<dim3(HDIM * KPAD / 256), 256, 0, stream>>>(Wih_ent, Wih3);
    mfma_gemm<0><<<dim3(VP / 128, PROJW / 128), 256, 0, stream>>>(
        embB, Wih3, proj, KPAD, KPAD, PROJW, KPAD);

    // ent GRU: 8 fused GEMM+epilogue step launches, ping-pong h
    bf16_t* hb[2] = { hEnt, hEnt2 };
    for (int t = 0; t < TE_; ++t)
        gru_step_fused<<<dim3(G / 128, 8), 512, 0, stream>>>(
            hb[t & 1], hb[(t + 1) & 1], Whh3_e, proj, ent_tok, ent_len,
            bih_ent, bhh_ent, TE_, t);

    // nodes = relu(h @ Wfc^T + bfc) — proper GEMM with gathered A rows
    fc_nodes_gemm<<<dim3(MROWS / 128, HDIM / 128), 256, 0, stream>>>(
        hEnt, hAtt[0], WfcB, bfc, nodes);

    // es/ed = nodes . asW/adW (one wave per row)
    esed_kernel<<<dim3(MROWS / 4), 256, 0, stream>>>(nodes, asW, adW, es, ed);

    // row-0 softmax + node mixing
    attn_mix_kernel<<<dim3(G), 256, 0, stream>>>(nodes, es, ed, mixed);

    // out = elu(mixed @ Wg^T)
    mfma_gemm<2><<<dim3(G / 128, HDIM / 128), 256, 0, stream>>>(
        mixed, WgB, out, HDIM, HDIM, HDIM, HDIM);
}